// Round 1
// baseline (129.824 us; speedup 1.0000x reference)
//
#include <hip/hip_runtime.h>
#include <hip/hip_bf16.h>

#define GN     8192
#define FIN    256
#define FOUT   64
#define GALPHA 0.2f
#define NSPLIT 8          // j-range splits for the main kernel (grid = 128*NSPLIT)
#define KCH    32         // j's per MFMA K-step

typedef float  f32x4  __attribute__((ext_vector_type(4)));
typedef __bf16 bf16x8 __attribute__((ext_vector_type(8)));

__device__ __forceinline__ float lrelu(float x) { return x > 0.f ? x : GALPHA * x; }

__device__ __forceinline__ unsigned short f2bf_rtne(float x) {
    unsigned int u = __float_as_uint(x);
    unsigned int r = (u + 0x7FFFu + ((u >> 16) & 1u)) >> 16;
    return (unsigned short)r;
}

// ---------------------------------------------------------------------------
// K1: Wh = h @ W  (fp32), f_src = Wh @ a[:64], f_dst = Wh @ a[64:]
// One block = 32 rows; W staged in LDS (64 KB); wave handles 8 rows, lane = col.
// ---------------------------------------------------------------------------
__global__ __launch_bounds__(256) void k_wh(const float* __restrict__ h,
                                            const float* __restrict__ W,
                                            const float* __restrict__ a,
                                            float* __restrict__ Wh,
                                            float* __restrict__ fsrc,
                                            float* __restrict__ fdst) {
    __shared__ float Wlds[FIN * FOUT];
    int t = threadIdx.x;
    for (int s = 0; s < FIN * FOUT / 4; s += 256) {
        *(float4*)&Wlds[(s + t) * 4] = *(const float4*)&W[(s + t) * 4];
    }
    __syncthreads();
    int wave = t >> 6, lane = t & 63;
    float a1 = a[lane], a2 = a[FOUT + lane];
    int i0 = blockIdx.x * 32 + wave * 8;
    for (int rr = 0; rr < 8; ++rr) {
        int i = i0 + rr;
        const float* hrow = h + (size_t)i * FIN;
        float acc = 0.f;
#pragma unroll 8
        for (int k = 0; k < FIN; k += 4) {
            float4 hv = *(const float4*)&hrow[k];
            acc += hv.x * Wlds[(k + 0) * FOUT + lane]
                 + hv.y * Wlds[(k + 1) * FOUT + lane]
                 + hv.z * Wlds[(k + 2) * FOUT + lane]
                 + hv.w * Wlds[(k + 3) * FOUT + lane];
        }
        Wh[(size_t)i * FOUT + lane] = acc;
        float v1 = acc * a1, v2 = acc * a2;
#pragma unroll
        for (int off = 32; off > 0; off >>= 1) {
            v1 += __shfl_xor(v1, off);
            v2 += __shfl_xor(v2, off);
        }
        if (lane == 0) { fsrc[i] = v1; fdst[i] = v2; }
    }
}

// ---------------------------------------------------------------------------
// K1s: global max of f_src (single block). Used as a safe row-softmax shift.
// ---------------------------------------------------------------------------
__global__ __launch_bounds__(1024) void k_smax(const float* __restrict__ fsrc,
                                               float* __restrict__ smax) {
    __shared__ float red[1024];
    int t = threadIdx.x;
    float m = -1e30f;
    for (int j = t; j < GN; j += 1024) m = fmaxf(m, fsrc[j]);
    red[t] = m;
    __syncthreads();
    for (int s = 512; s > 0; s >>= 1) {
        if (t < s) red[t] = fmaxf(red[t], red[t + s]);
        __syncthreads();
    }
    if (t == 0) smax[0] = red[0];
}

// ---------------------------------------------------------------------------
// K1b: repack Wh (fp32) into bf16 MFMA B-fragment layout:
//   frag[jblk][ct][lane] (uint4 = 8 bf16) = Wh[jblk*32 + (lane>>4)*8 + e][ct*16 + (lane&15)]
// so k_attn's B loads are a single coalesced dwordx4 per wave per col-tile.
// ---------------------------------------------------------------------------
__global__ __launch_bounds__(256) void k_pack(const float* __restrict__ Wh,
                                              uint4* __restrict__ whfrag) {
    int u = blockIdx.x * 256 + threadIdx.x;          // 0 .. 65535
    int lane = u & 63, ct = (u >> 6) & 3, jblk = u >> 8;
    int jr  = jblk * 32 + ((lane >> 4) << 3);
    int col = ct * 16 + (lane & 15);
    unsigned int pk[4];
#pragma unroll
    for (int p = 0; p < 4; ++p) {
        unsigned int lo = f2bf_rtne(Wh[(size_t)(jr + 2 * p) * FOUT + col]);
        unsigned int hi = f2bf_rtne(Wh[(size_t)(jr + 2 * p + 1) * FOUT + col]);
        pk[p] = lo | (hi << 16);
    }
    uint4 o; o.x = pk[0]; o.y = pk[1]; o.z = pk[2]; o.w = pk[3];
    whfrag[u] = o;
}

// ---------------------------------------------------------------------------
// K2: main fused kernel. Block = 64 rows x 1024-j segment. 4 waves, wave = 16 rows.
// Per lane: row r = lane&15, k-group g = lane>>4; computes its 8 P-weights per
// 32-j chunk directly into the MFMA A-fragment. Single pass over adj.
// ---------------------------------------------------------------------------
__global__ __launch_bounds__(256) void k_attn(const int* __restrict__ adj,
                                              const float* __restrict__ fsrc,
                                              const float* __restrict__ fdst,
                                              const float* __restrict__ smaxp,
                                              const uint4* __restrict__ whfrag,
                                              float* __restrict__ pacc,
                                              float* __restrict__ pden) {
    int bid = blockIdx.x;
    int rt = bid >> 3;               // row tile 0..127
    int q  = bid & (NSPLIT - 1);     // j split 0..7
    int wv   = threadIdx.x >> 6;
    int lane = threadIdx.x & 63;
    int r = lane & 15, g = lane >> 4;
    int irow = rt * 64 + wv * 16 + r;        // A-fragment row of this lane

    float smax = smaxp[0];
    float d  = fdst[irow];
    float ci = lrelu(d + smax);              // upper bound of row max -> exp args <= 0

    const int jseg  = GN / NSPLIT;           // 1024
    const int jbase = q * jseg;
    const int*   arow = adj  + (size_t)irow * GN + jbase + g * 8;
    const float* sp   = fsrc + jbase + g * 8;

    f32x4 acc0 = {0.f,0.f,0.f,0.f}, acc1 = acc0, acc2 = acc0, acc3 = acc0;
    float den = 0.f;

    const int NCH = jseg / KCH;              // 32 chunks
    int4   A0 = *(const int4*)(arow);
    int4   A1 = *(const int4*)(arow + 4);
    float4 S0 = *(const float4*)(sp);
    float4 S1 = *(const float4*)(sp + 4);

    for (int ch = 0; ch < NCH; ++ch) {
        int pn = (ch + 1 < NCH) ? (ch + 1) : ch;   // prefetch next chunk
        int4   nA0 = *(const int4*)(arow + pn * KCH);
        int4   nA1 = *(const int4*)(arow + pn * KCH + 4);
        float4 nS0 = *(const float4*)(sp + pn * KCH);
        float4 nS1 = *(const float4*)(sp + pn * KCH + 4);

        float se[8] = {S0.x, S0.y, S0.z, S0.w, S1.x, S1.y, S1.z, S1.w};
        int   ae[8] = {A0.x, A0.y, A0.z, A0.w, A1.x, A1.y, A1.z, A1.w};
        bf16x8 afrag;
        float wsum = 0.f;
#pragma unroll
        for (int e = 0; e < 8; ++e) {
            float ev = lrelu(d + se[e]) - ci;          // <= 0
            float wvv = (ae[e] > 0) ? __expf(ev) : 0.f;
            wsum += wvv;
            afrag[e] = (__bf16)wvv;
        }
        den += wsum;

        const uint4* bp = whfrag + ((size_t)(jbase + ch * KCH) >> 5) * 256 + lane;
        uint4 b0 = bp[0], b1 = bp[64], b2 = bp[128], b3 = bp[192];
        acc0 = __builtin_amdgcn_mfma_f32_16x16x32_bf16(afrag, __builtin_bit_cast(bf16x8, b0), acc0, 0, 0, 0);
        acc1 = __builtin_amdgcn_mfma_f32_16x16x32_bf16(afrag, __builtin_bit_cast(bf16x8, b1), acc1, 0, 0, 0);
        acc2 = __builtin_amdgcn_mfma_f32_16x16x32_bf16(afrag, __builtin_bit_cast(bf16x8, b2), acc2, 0, 0, 0);
        acc3 = __builtin_amdgcn_mfma_f32_16x16x32_bf16(afrag, __builtin_bit_cast(bf16x8, b3), acc3, 0, 0, 0);

        A0 = nA0; A1 = nA1; S0 = nS0; S1 = nS1;
    }

    // row denominator: sum the 4 k-groups (lanes r, r+16, r+32, r+48)
    den += __shfl_xor(den, 16);
    den += __shfl_xor(den, 32);

    // store partial accumulators. D layout: col = lane&15 (= r), row = g*4 + reg
    float* po = pacc + (size_t)q * (GN * FOUT);
    int orow = rt * 64 + wv * 16 + g * 4;
#pragma unroll
    for (int reg = 0; reg < 4; ++reg) {
        po[(size_t)(orow + reg) * FOUT +  0 + r] = acc0[reg];
        po[(size_t)(orow + reg) * FOUT + 16 + r] = acc1[reg];
        po[(size_t)(orow + reg) * FOUT + 32 + r] = acc2[reg];
        po[(size_t)(orow + reg) * FOUT + 48 + r] = acc3[reg];
    }
    if (g == 0) pden[(size_t)q * GN + irow] = den;
}

// ---------------------------------------------------------------------------
// K3: combine partials, divide by denominator, ELU.
// ---------------------------------------------------------------------------
__global__ __launch_bounds__(256) void k_out(const float* __restrict__ pacc,
                                             const float* __restrict__ pden,
                                             float* __restrict__ out) {
    int idx = blockIdx.x * 256 + threadIdx.x;
    int i = idx >> 6;
    float num = 0.f, den = 0.f;
#pragma unroll
    for (int qq = 0; qq < NSPLIT; ++qq) {
        num += pacc[(size_t)qq * (GN * FOUT) + idx];
        den += pden[(size_t)qq * GN + i];
    }
    float v = (den != 0.f) ? num / den : 0.f;
    out[idx] = v > 0.f ? v : __expf(v) - 1.f;
}

// ---------------------------------------------------------------------------
extern "C" void kernel_launch(void* const* d_in, const int* in_sizes, int n_in,
                              void* d_out, int out_size, void* d_ws, size_t ws_size,
                              hipStream_t stream) {
    const float* h   = (const float*)d_in[0];
    const int*   adj = (const int*)d_in[1];
    const float* W   = (const float*)d_in[2];
    const float* a   = (const float*)d_in[3];
    float* out = (float*)d_out;

    float* ws     = (float*)d_ws;
    float* Wh     = ws;                                  // 524288 f
    float* fsrc   = Wh + (size_t)GN * FOUT;              // 8192 f
    float* fdst   = fsrc + GN;                           // 8192 f
    float* smax   = fdst + GN;                           // 64 f (pad)
    float* whfrag = smax + 64;                           // 262144 f (bf16 payload)
    float* pacc   = whfrag + (size_t)GN * FOUT / 2;      // NSPLIT*524288 f
    float* pden   = pacc + (size_t)NSPLIT * GN * FOUT;   // NSPLIT*8192 f

    k_wh  <<<GN / 32,              256, 0, stream>>>(h, W, a, Wh, fsrc, fdst);
    k_smax<<<1,                   1024, 0, stream>>>(fsrc, smax);
    k_pack<<<(GN / 32) * 4 * 64 / 256, 256, 0, stream>>>(Wh, (uint4*)whfrag);
    k_attn<<<(GN / 64) * NSPLIT,   256, 0, stream>>>(adj, fsrc, fdst, smax,
                                                     (const uint4*)whfrag, pacc, pden);
    k_out <<<GN * FOUT / 256,      256, 0, stream>>>(pacc, pden, out);
}

// Round 2
// 119.141 us; speedup vs baseline: 1.0897x; 1.0897x over previous
//
#include <hip/hip_runtime.h>
#include <hip/hip_bf16.h>

#define GN   8192
#define FIN  256
#define FOUT 64
#define SEGJ 1024
#define NSEG 8

typedef float  f32x4  __attribute__((ext_vector_type(4)));
typedef __bf16 bf16x8 __attribute__((ext_vector_type(8)));
typedef int    iv4    __attribute__((ext_vector_type(4)));

__device__ __forceinline__ unsigned short f2bf_rtne(float x) {
    unsigned int u = __float_as_uint(x);
    unsigned int r = (u + 0x7FFFu + ((u >> 16) & 1u)) >> 16;
    return (unsigned short)r;
}

// ---------------------------------------------------------------------------
// K1: Wh = h @ W (fp32, W^T staged in LDS, ds_read_b128), f_src/f_dst row dots,
// then pack this block's 32 Wh rows into bf16 MFMA B-fragment layout.
// Block = 32 rows (jblk == blockIdx.x), 256 threads. Wh never hits HBM.
// ---------------------------------------------------------------------------
__global__ __launch_bounds__(256) void k_wh(const float* __restrict__ h,
                                            const float* __restrict__ W,
                                            const float* __restrict__ a,
                                            float* __restrict__ fsrc,
                                            float* __restrict__ fdst,
                                            uint4* __restrict__ whfrag) {
    __shared__ float Wt[FOUT][FIN + 1];   // transposed W, +1 pad: 2-way banks (free)
    __shared__ float WhL[32][FOUT + 1];
    int t = threadIdx.x;
    int col = t & 63, kq4 = t >> 6;
#pragma unroll
    for (int rep = 0; rep < 16; ++rep) {
        int k0 = kq4 * 4 + rep * 16;
        float4 wv;
        wv.x = W[(k0 + 0) * FOUT + col];
        wv.y = W[(k0 + 1) * FOUT + col];
        wv.z = W[(k0 + 2) * FOUT + col];
        wv.w = W[(k0 + 3) * FOUT + col];
        *(float4*)&Wt[col][k0] = wv;
    }
    __syncthreads();
    int wave = t >> 6, lane = t & 63;
    float a1 = a[lane], a2 = a[FOUT + lane];
    int bid = blockIdx.x;
#pragma unroll
    for (int rr = 0; rr < 8; ++rr) {
        int il = wave * 8 + rr;
        int i  = bid * 32 + il;
        const float* hrow = h + (size_t)i * FIN;
        float acc = 0.f;
#pragma unroll 8
        for (int k0 = 0; k0 < FIN; k0 += 4) {
            float4 hv = *(const float4*)&hrow[k0];
            float4 wv = *(const float4*)&Wt[lane][k0];
            acc += hv.x * wv.x + hv.y * wv.y + hv.z * wv.z + hv.w * wv.w;
        }
        WhL[il][lane] = acc;
        float v1 = acc * a1, v2 = acc * a2;
#pragma unroll
        for (int off = 32; off > 0; off >>= 1) {
            v1 += __shfl_xor(v1, off);
            v2 += __shfl_xor(v2, off);
        }
        // clamp: softmax is scale-invariant, only overflow protection needed
        if (lane == 0) { fsrc[i] = fminf(v1, 30.f); fdst[i] = fminf(v2, 30.f); }
    }
    __syncthreads();
    // pack: frag[jblk=bid][ct][lane] (8 bf16) = Wh[bid*32+(lane>>4)*8+e][ct*16+(lane&15)]
    int lane2 = t & 63, ct = t >> 6;
    int colc = ct * 16 + (lane2 & 15);
    int rbase = (lane2 >> 4) * 8;
    unsigned int pk[4];
#pragma unroll
    for (int p = 0; p < 4; ++p) {
        unsigned int lo = f2bf_rtne(WhL[rbase + 2 * p    ][colc]);
        unsigned int hi = f2bf_rtne(WhL[rbase + 2 * p + 1][colc]);
        pk[p] = lo | (hi << 16);
    }
    uint4 o; o.x = pk[0]; o.y = pk[1]; o.z = pk[2]; o.w = pk[3];
    whfrag[(size_t)(bid * 4 + ct) * 64 + lane2] = o;
}

// ---------------------------------------------------------------------------
// Producer: stream one 1024-j segment of adj for the block's 32 rows,
// ballot-compress to bits, write LDS. Unit = 256 consecutive ints (1 KB/instr).
// Bit layout per seg: word[(Q*8 + c*2 + h)*33 + row]; j = Q*256 + l*4 + c,
// word h of ballot B_c holds lanes l = h*32..h*32+31.
// ---------------------------------------------------------------------------
__device__ __forceinline__ void produce_seg(const int* __restrict__ adj, int rowbase, int S,
                                            unsigned* __restrict__ bbuf, int wv, int lane) {
    const int* base = adj + (size_t)rowbase * GN + (size_t)S * SEGJ;
    iv4 st[32];
#pragma unroll
    for (int k = 0; k < 32; ++k) {
        int u = wv * 32 + k;
        st[k] = __builtin_nontemporal_load(
            (const iv4*)(base + (size_t)(u >> 2) * GN + (u & 3) * 256 + lane * 4));
    }
#pragma unroll
    for (int k = 0; k < 32; ++k) {
        int u = wv * 32 + k, row = u >> 2, Q = u & 3;
        unsigned long long b0 = __ballot(st[k][0] > 0);
        unsigned long long b1 = __ballot(st[k][1] > 0);
        unsigned long long b2 = __ballot(st[k][2] > 0);
        unsigned long long b3 = __ballot(st[k][3] > 0);
        if (lane < 8) {
            int c = lane >> 1, hh = lane & 1;
            unsigned long long bs = (c == 0) ? b0 : (c == 1) ? b1 : (c == 2) ? b2 : b3;
            bbuf[(Q * 8 + lane) * 33 + row] = (unsigned)(bs >> (hh * 32));
        }
    }
}

// ---------------------------------------------------------------------------
// K2: fused GAT kernel. Block = 32 rows, 512 threads.
// Waves 0-3: produce adj bitmask segments (double-buffered LDS).
// Waves 4-7: consume — (m = row-frag, p = chunk parity); weights computed
// in-register into MFMA A-fragments; full-j accumulation; epilogue reduces
// p-partials via LDS, divides by softmax denom, ELU, writes out.
// ---------------------------------------------------------------------------
__global__ __launch_bounds__(512, 2) void k_fused(const int* __restrict__ adj,
                                                  const float* __restrict__ fsrc,
                                                  const float* __restrict__ fdst,
                                                  const uint4* __restrict__ whfrag,
                                                  float* __restrict__ out) {
    __shared__ unsigned bitsS[2][1056];
    __shared__ __align__(16) float redS[4][64][20];
    __shared__ float denS[2][2][16];
    int t = threadIdx.x, wv = t >> 6, lane = t & 63;
    int rowbase = blockIdx.x * 32;

    f32x4 acc0 = {0.f, 0.f, 0.f, 0.f}, acc1 = acc0, acc2 = acc0, acc3 = acc0;
    float den = 0.f;
    int m = (wv - 4) >> 1, p = (wv - 4) & 1;
    int r = lane & 15, g = lane >> 4;
    float d = 0.f;
    if (wv >= 4) d = fdst[rowbase + m * 16 + r];

    if (wv < 4) produce_seg(adj, rowbase, 0, bitsS[0], wv, lane);
    __syncthreads();

    for (int S = 0; S < NSEG; ++S) {
        if (wv < 4) {
            if (S + 1 < NSEG) produce_seg(adj, rowbase, S + 1, bitsS[(S + 1) & 1], wv, lane);
        } else {
            const unsigned* bbuf = bitsS[S & 1];
            int jb0 = S * 32;
            int ch = p;
            const uint4* bp = whfrag + (size_t)(jb0 + ch) * 256 + lane;
            uint4 b0 = bp[0], b1 = bp[64], b2 = bp[128], b3 = bp[192];
            const float* sp = fsrc + S * SEGJ + ch * 32 + g * 8;
            float4 s0 = *(const float4*)sp, s1 = *(const float4*)(sp + 4);
            int row = m * 16 + r;
#pragma unroll 4
            for (int k = 0; k < 16; ++k) {
                int chn = (k < 15) ? ch + 2 : ch;
                const uint4* bpn = whfrag + (size_t)(jb0 + chn) * 256 + lane;
                uint4 nb0 = bpn[0], nb1 = bpn[64], nb2 = bpn[128], nb3 = bpn[192];
                const float* spn = fsrc + S * SEGJ + chn * 32 + g * 8;
                float4 ns0 = *(const float4*)spn, ns1 = *(const float4*)(spn + 4);

                int Q = ch >> 3, hh = (ch >> 2) & 1, sh = (ch & 3) * 8 + g * 2;
                int wb = (Q * 8 + hh) * 33 + row;
                unsigned wcs[4] = {bbuf[wb], bbuf[wb + 66], bbuf[wb + 132], bbuf[wb + 198]};

                float se[8] = {s0.x, s0.y, s0.z, s0.w, s1.x, s1.y, s1.z, s1.w};
                bf16x8 af;
                float ws = 0.f;
#pragma unroll
                for (int e = 0; e < 8; ++e) {
                    float ev = d + se[e];
                    float lr = fmaxf(ev, 0.2f * ev);         // leakyrelu (no shift needed)
                    float ex = __expf(lr);
                    unsigned bit = (wcs[e & 3] >> (sh + (e >> 2))) & 1u;
                    float wvv = bit ? ex : 0.f;
                    ws += wvv;
                    af[e] = (__bf16)wvv;
                }
                den += ws;
                acc0 = __builtin_amdgcn_mfma_f32_16x16x32_bf16(af, __builtin_bit_cast(bf16x8, b0), acc0, 0, 0, 0);
                acc1 = __builtin_amdgcn_mfma_f32_16x16x32_bf16(af, __builtin_bit_cast(bf16x8, b1), acc1, 0, 0, 0);
                acc2 = __builtin_amdgcn_mfma_f32_16x16x32_bf16(af, __builtin_bit_cast(bf16x8, b2), acc2, 0, 0, 0);
                acc3 = __builtin_amdgcn_mfma_f32_16x16x32_bf16(af, __builtin_bit_cast(bf16x8, b3), acc3, 0, 0, 0);
                ch = chn; b0 = nb0; b1 = nb1; b2 = nb2; b3 = nb3; s0 = ns0; s1 = ns1;
            }
        }
        __syncthreads();
    }

    // epilogue: consumers deposit partials
    if (wv >= 4) {
        int cw = wv - 4;
        *(f32x4*)&redS[cw][lane][0]  = acc0;
        *(f32x4*)&redS[cw][lane][4]  = acc1;
        *(f32x4*)&redS[cw][lane][8]  = acc2;
        *(f32x4*)&redS[cw][lane][12] = acc3;
        den += __shfl_xor(den, 16);
        den += __shfl_xor(den, 32);
        if (lane < 16) denS[m][p][lane] = den;
    }
    __syncthreads();

    // all 512 threads: 4 outputs each (row = t>>4, cols (t&15)*4 ..+3)
    {
        int row = t >> 4;
        int c0  = (t & 15) * 4;
        int mm = row >> 4, q = (row >> 2) & 3, reg = row & 3;
        float dd = denS[mm][0][row & 15] + denS[mm][1][row & 15];
        float inv = (dd != 0.f) ? 1.f / dd : 0.f;
        float4 o;
        float* op = &o.x;
#pragma unroll
        for (int cc = 0; cc < 4; ++cc) {
            int col = c0 + cc;
            int l   = q * 16 + (col & 15);
            int idx = (col >> 4) * 4 + reg;
            float num = redS[mm * 2 + 0][l][idx] + redS[mm * 2 + 1][l][idx];
            float v = num * inv;
            op[cc] = v > 0.f ? v : __expf(v) - 1.f;   // ELU
        }
        *(float4*)&out[(size_t)(rowbase + row) * FOUT + c0] = o;
    }
}

// ---------------------------------------------------------------------------
extern "C" void kernel_launch(void* const* d_in, const int* in_sizes, int n_in,
                              void* d_out, int out_size, void* d_ws, size_t ws_size,
                              hipStream_t stream) {
    (void)in_sizes; (void)n_in; (void)out_size; (void)ws_size;
    const float* h   = (const float*)d_in[0];
    const int*   adj = (const int*)d_in[1];
    const float* W   = (const float*)d_in[2];
    const float* a   = (const float*)d_in[3];
    float* out = (float*)d_out;

    float* ws     = (float*)d_ws;
    float* fsrc   = ws;                         // 8192 f
    float* fdst   = ws + GN;                    // 8192 f
    uint4* whfrag = (uint4*)(ws + 2 * GN);      // 65536 uint4 = 1 MB

    k_wh   <<<GN / 32, 256, 0, stream>>>(h, W, a, fsrc, fdst, whfrag);
    k_fused<<<GN / 32, 512, 0, stream>>>(adj, fsrc, fdst, whfrag, out);
}

// Round 4
// 113.099 us; speedup vs baseline: 1.1479x; 1.0534x over previous
//
#include <hip/hip_runtime.h>
#include <hip/hip_bf16.h>

#define GN     8192
#define FIN    256
#define FOUT   64
#define NSPLIT 8
#define JSEG   1024      // j columns per split
#define NCH    32        // 32-j chunks per segment
#define PF     4         // adj prefetch depth (chunks)
#define ROWS_B 128       // rows per k_attn block = 8 waves x 16
#define LOG2E  1.44269504f

typedef float  f32x4  __attribute__((ext_vector_type(4)));
typedef __bf16 bf16x8 __attribute__((ext_vector_type(8)));
typedef int    iv4    __attribute__((ext_vector_type(4)));

__device__ __forceinline__ unsigned short f2bf_rtne(float x) {
    unsigned int u = __float_as_uint(x);
    unsigned int r = (u + 0x7FFFu + ((u >> 16) & 1u)) >> 16;
    return (unsigned short)r;
}

// ---------------------------------------------------------------------------
// K1: Wh = h @ W (fp32), f_src/f_dst (pre-scaled by log2(e), clamped), and
// pack this block's 32 Wh rows into bf16 MFMA B-fragment layout.
// Block = 32 rows (jblk == blockIdx.x), 256 threads. Wh never hits HBM.
// ---------------------------------------------------------------------------
__global__ __launch_bounds__(256) void k_wh(const float* __restrict__ h,
                                            const float* __restrict__ W,
                                            const float* __restrict__ a,
                                            float* __restrict__ fsrc,
                                            float* __restrict__ fdst,
                                            uint4* __restrict__ whfrag) {
    __shared__ float Wt[FOUT][FIN + 1];
    __shared__ float WhL[32][FOUT + 1];
    int t = threadIdx.x;
    int col = t & 63, kq4 = t >> 6;
#pragma unroll
    for (int rep = 0; rep < 16; ++rep) {
        int k0 = kq4 * 4 + rep * 16;
        float4 wv;
        wv.x = W[(k0 + 0) * FOUT + col];
        wv.y = W[(k0 + 1) * FOUT + col];
        wv.z = W[(k0 + 2) * FOUT + col];
        wv.w = W[(k0 + 3) * FOUT + col];
        *(float4*)&Wt[col][k0] = wv;
    }
    __syncthreads();
    int wave = t >> 6, lane = t & 63;
    float a1 = a[lane], a2 = a[FOUT + lane];
    int bid = blockIdx.x;
#pragma unroll
    for (int rr = 0; rr < 8; ++rr) {
        int il = wave * 8 + rr;
        int i  = bid * 32 + il;
        const float* hrow = h + (size_t)i * FIN;
        float acc = 0.f;
#pragma unroll 8
        for (int k0 = 0; k0 < FIN; k0 += 4) {
            float4 hv = *(const float4*)&hrow[k0];
            float4 wv = *(const float4*)&Wt[lane][k0];
            acc += hv.x * wv.x + hv.y * wv.y + hv.z * wv.z + hv.w * wv.w;
        }
        WhL[il][lane] = acc;
        float v1 = acc * a1, v2 = acc * a2;
#pragma unroll
        for (int off = 32; off > 0; off >>= 1) {
            v1 += __shfl_xor(v1, off);
            v2 += __shfl_xor(v2, off);
        }
        // clamp (overflow insurance; softmax is scale-invariant) + log2e pre-scale
        if (lane == 0) {
            fsrc[i] = fminf(v1, 30.f) * LOG2E;
            fdst[i] = fminf(v2, 30.f) * LOG2E;
        }
    }
    __syncthreads();
    // pack: frag[jblk=bid][ct][lane] (8 bf16) = Wh[bid*32+(lane>>4)*8+e][ct*16+(lane&15)]
    int lane2 = t & 63, ct = t >> 6;
    int colc = ct * 16 + (lane2 & 15);
    int rbase = (lane2 >> 4) * 8;
    unsigned int pk[4];
#pragma unroll
    for (int p = 0; p < 4; ++p) {
        unsigned int lo = f2bf_rtne(WhL[rbase + 2 * p    ][colc]);
        unsigned int hi = f2bf_rtne(WhL[rbase + 2 * p + 1][colc]);
        pk[p] = lo | (hi << 16);
    }
    uint4 o; o.x = pk[0]; o.y = pk[1]; o.z = pk[2]; o.w = pk[3];
    whfrag[(size_t)(bid * 4 + ct) * 64 + lane2] = o;
}

// ---------------------------------------------------------------------------
// K2: attention + PV. Block = 128 rows x 1024-j split. 8 waves x 16 rows
// (disjoint). B-fragments + fsrc slice staged in LDS (132 KB) once, so the
// main loop's ONLY vmem stream is adj: depth-PF register prefetch with
// compiler-counted vmcnt waits, no barriers in the loop.
// ---------------------------------------------------------------------------
__global__ __launch_bounds__(512, 2) void k_attn(const int* __restrict__ adj,
                                                 const float* __restrict__ fsrc,
                                                 const float* __restrict__ fdst,
                                                 const uint4* __restrict__ whfrag,
                                                 float* __restrict__ pacc,
                                                 float* __restrict__ pden) {
    __shared__ uint4 whL[NCH * 4 * 64];   // 128 KB: B-fragments for this j-split
    __shared__ float fsL[JSEG];           // 4 KB

    int t = threadIdx.x, wv = t >> 6, lane = t & 63;
    int bid = blockIdx.x;
    int rt = bid >> 3, q = bid & (NSPLIT - 1);
    int rowbase = rt * ROWS_B;

    // stage B-fragment slice + fsrc slice
    {
        const uint4* src = whfrag + (size_t)q * (NCH * 4 * 64);
#pragma unroll
        for (int it = 0; it < 16; ++it) whL[it * 512 + t] = src[it * 512 + t];
        if (t < 256) *(float4*)&fsL[t * 4] = *(const float4*)&fsrc[q * JSEG + t * 4];
    }
    __syncthreads();

    int r = lane & 15, g = lane >> 4;
    int row = rowbase + wv * 16 + r;
    float d = fdst[row];
    const int* arow = adj + (size_t)row * GN + q * JSEG + g * 8;

    f32x4 acc0 = {0.f, 0.f, 0.f, 0.f}, acc1 = acc0, acc2 = acc0, acc3 = acc0;
    float den = 0.f;

    iv4 pfa[PF], pfb[PF];
#pragma unroll
    for (int dd = 0; dd < PF; ++dd) {
        pfa[dd] = __builtin_nontemporal_load((const iv4*)(arow + dd * 32));
        pfb[dd] = __builtin_nontemporal_load((const iv4*)(arow + dd * 32 + 4));
    }

    for (int cb = 0; cb < NCH; cb += PF) {
#pragma unroll
        for (int dd = 0; dd < PF; ++dd) {
            int ch = cb + dd;
            int ae[8] = {pfa[dd][0], pfa[dd][1], pfa[dd][2], pfa[dd][3],
                         pfb[dd][0], pfb[dd][1], pfb[dd][2], pfb[dd][3]};
            float4 s0 = *(const float4*)&fsL[ch * 32 + g * 8];
            float4 s1 = *(const float4*)&fsL[ch * 32 + g * 8 + 4];
            float se[8] = {s0.x, s0.y, s0.z, s0.w, s1.x, s1.y, s1.z, s1.w};

            // issue next adj chunk (wave-uniform guard; counted vmcnt keeps it async)
            int nch = ch + PF;
            if (nch < NCH) {
                pfa[dd] = __builtin_nontemporal_load((const iv4*)(arow + nch * 32));
                pfb[dd] = __builtin_nontemporal_load((const iv4*)(arow + nch * 32 + 4));
            }

            bf16x8 af;
            float ws = 0.f;
#pragma unroll
            for (int e = 0; e < 8; ++e) {
                float ev = d + se[e];                       // already log2e-scaled
                float lr = fmaxf(ev, 0.2f * ev);            // leakyrelu (scale-equivariant)
                float ex = __builtin_amdgcn_exp2f(lr);      // == exp(lrelu(d+s))
                float wvv = (ae[e] > 0) ? ex : 0.f;
                ws += wvv;
                af[e] = (__bf16)wvv;
            }
            den += ws;

            const uint4* bl = &whL[(ch * 4) * 64 + lane];
            uint4 b0 = bl[0], b1 = bl[64], b2 = bl[128], b3 = bl[192];
            acc0 = __builtin_amdgcn_mfma_f32_16x16x32_bf16(af, __builtin_bit_cast(bf16x8, b0), acc0, 0, 0, 0);
            acc1 = __builtin_amdgcn_mfma_f32_16x16x32_bf16(af, __builtin_bit_cast(bf16x8, b1), acc1, 0, 0, 0);
            acc2 = __builtin_amdgcn_mfma_f32_16x16x32_bf16(af, __builtin_bit_cast(bf16x8, b2), acc2, 0, 0, 0);
            acc3 = __builtin_amdgcn_mfma_f32_16x16x32_bf16(af, __builtin_bit_cast(bf16x8, b3), acc3, 0, 0, 0);
        }
    }

    // row denominator across the 4 k-groups
    den += __shfl_xor(den, 16);
    den += __shfl_xor(den, 32);

    // store partials. D layout: col = lane&15 (= r), row = g*4 + reg
    float* po = pacc + (size_t)q * (GN * FOUT);
    int orow = rowbase + wv * 16 + g * 4;
#pragma unroll
    for (int reg = 0; reg < 4; ++reg) {
        po[(size_t)(orow + reg) * FOUT +  0 + r] = acc0[reg];
        po[(size_t)(orow + reg) * FOUT + 16 + r] = acc1[reg];
        po[(size_t)(orow + reg) * FOUT + 32 + r] = acc2[reg];
        po[(size_t)(orow + reg) * FOUT + 48 + r] = acc3[reg];
    }
    if (g == 0) pden[(size_t)q * GN + row] = den;
}

// ---------------------------------------------------------------------------
// K3: combine partials, divide by denominator, ELU.
// ---------------------------------------------------------------------------
__global__ __launch_bounds__(256) void k_out(const float* __restrict__ pacc,
                                             const float* __restrict__ pden,
                                             float* __restrict__ out) {
    int idx = blockIdx.x * 256 + threadIdx.x;
    int i = idx >> 6;
    float num = 0.f, den = 0.f;
#pragma unroll
    for (int qq = 0; qq < NSPLIT; ++qq) {
        num += pacc[(size_t)qq * (GN * FOUT) + idx];
        den += pden[(size_t)qq * GN + i];
    }
    float v = (den != 0.f) ? num / den : 0.f;
    out[idx] = v > 0.f ? v : __expf(v) - 1.f;
}

// ---------------------------------------------------------------------------
extern "C" void kernel_launch(void* const* d_in, const int* in_sizes, int n_in,
                              void* d_out, int out_size, void* d_ws, size_t ws_size,
                              hipStream_t stream) {
    (void)in_sizes; (void)n_in; (void)out_size; (void)ws_size;
    const float* h   = (const float*)d_in[0];
    const int*   adj = (const int*)d_in[1];
    const float* W   = (const float*)d_in[2];
    const float* a   = (const float*)d_in[3];
    float* out = (float*)d_out;

    float* ws     = (float*)d_ws;
    float* fsrc   = ws;                                  // 8192 f
    float* fdst   = fsrc + GN;                           // 8192 f
    uint4* whfrag = (uint4*)(fdst + GN);                 // 65536 uint4 = 1 MB
    float* pacc   = (float*)(whfrag + (size_t)GN / 32 * 4 * 64); // NSPLIT*524288 f
    float* pden   = pacc + (size_t)NSPLIT * GN * FOUT;   // NSPLIT*8192 f

    k_wh  <<<GN / 32,                    256, 0, stream>>>(h, W, a, fsrc, fdst, whfrag);
    k_attn<<<(GN / ROWS_B) * NSPLIT,     512, 0, stream>>>(adj, fsrc, fdst, whfrag, pacc, pden);
    k_out <<<GN * FOUT / 256,            256, 0, stream>>>(pacc, pden, out);
}

// Round 5
// 106.220 us; speedup vs baseline: 1.2222x; 1.0648x over previous
//
#include <hip/hip_runtime.h>
#include <hip/hip_bf16.h>

#define GN     8192
#define FIN    256
#define FOUT   64
#define NSPLIT 8
#define JSEG   1024      // j columns per split
#define NCH    32        // 32-j chunks per segment
#define PF     4         // adj prefetch depth (chunks)
#define ROWS_B 128       // rows per k_attn block = 8 waves x 16
#define LOG2E  1.44269504f

typedef float  f32x4  __attribute__((ext_vector_type(4)));
typedef __bf16 bf16x8 __attribute__((ext_vector_type(8)));
typedef int    iv4    __attribute__((ext_vector_type(4)));

__device__ __forceinline__ unsigned short f2bf_rtne(float x) {
    unsigned int u = __float_as_uint(x);
    unsigned int r = (u + 0x7FFFu + ((u >> 16) & 1u)) >> 16;
    return (unsigned short)r;
}

// ---------------------------------------------------------------------------
// K1: Wh = h @ W (fp32), f_src/f_dst (pre-scaled by log2(e), clamped), and
// pack this block's 32 Wh rows into bf16 MFMA B-fragment layout with the
// line-friendly within-chunk permutation:
//   k-index k = gb*8 + e  <->  j (row within 32-block) = gb*4 + (e&3) + (e>>2)*16
// Block = 32 rows (jblk == blockIdx.x), 256 threads. Wh never hits HBM.
// ---------------------------------------------------------------------------
__global__ __launch_bounds__(256) void k_wh(const float* __restrict__ h,
                                            const float* __restrict__ W,
                                            const float* __restrict__ a,
                                            float* __restrict__ fsrc,
                                            float* __restrict__ fdst,
                                            uint4* __restrict__ whfrag) {
    __shared__ float Wt[FOUT][FIN + 1];
    __shared__ float WhL[32][FOUT + 1];
    int t = threadIdx.x;
    int col = t & 63, kq4 = t >> 6;
#pragma unroll
    for (int rep = 0; rep < 16; ++rep) {
        int k0 = kq4 * 4 + rep * 16;
        float4 wv;
        wv.x = W[(k0 + 0) * FOUT + col];
        wv.y = W[(k0 + 1) * FOUT + col];
        wv.z = W[(k0 + 2) * FOUT + col];
        wv.w = W[(k0 + 3) * FOUT + col];
        *(float4*)&Wt[col][k0] = wv;
    }
    __syncthreads();
    int wave = t >> 6, lane = t & 63;
    float a1 = a[lane], a2 = a[FOUT + lane];
    int bid = blockIdx.x;
#pragma unroll
    for (int rr = 0; rr < 8; ++rr) {
        int il = wave * 8 + rr;
        int i  = bid * 32 + il;
        const float* hrow = h + (size_t)i * FIN;
        float acc = 0.f;
#pragma unroll 8
        for (int k0 = 0; k0 < FIN; k0 += 4) {
            float4 hv = *(const float4*)&hrow[k0];
            float4 wv = *(const float4*)&Wt[lane][k0];
            acc += hv.x * wv.x + hv.y * wv.y + hv.z * wv.z + hv.w * wv.w;
        }
        WhL[il][lane] = acc;
        float v1 = acc * a1, v2 = acc * a2;
#pragma unroll
        for (int off = 32; off > 0; off >>= 1) {
            v1 += __shfl_xor(v1, off);
            v2 += __shfl_xor(v2, off);
        }
        // clamp (overflow insurance; softmax is scale-invariant) + log2e pre-scale
        if (lane == 0) {
            fsrc[i] = fminf(v1, 30.f) * LOG2E;
            fdst[i] = fminf(v2, 30.f) * LOG2E;
        }
    }
    __syncthreads();
    // pack B-fragments with the permuted k->j mapping
    int lane2 = t & 63, ct = t >> 6;
    int colc = ct * 16 + (lane2 & 15);
    int gb = lane2 >> 4;
    unsigned int pk[4];
#pragma unroll
    for (int p = 0; p < 4; ++p) {
        int jo = ((p >> 1) * 16) + gb * 4 + (p & 1) * 2;   // row of even element
        unsigned int lo = f2bf_rtne(WhL[jo    ][colc]);
        unsigned int hi = f2bf_rtne(WhL[jo + 1][colc]);
        pk[p] = lo | (hi << 16);
    }
    uint4 o; o.x = pk[0]; o.y = pk[1]; o.z = pk[2]; o.w = pk[3];
    whfrag[(size_t)(bid * 4 + ct) * 64 + lane2] = o;
}

// ---------------------------------------------------------------------------
// K2: attention + PV. Block = 128 rows x 1024-j split. 8 waves x 16 rows
// (disjoint). B-fragments + fsrc slice staged in LDS (132 KB); main loop's
// only vmem stream is adj. Per instruction, each row's 4 lanes now cover one
// FULL contiguous 64B line (j = g*4 + (e&3) + (e>>2)*16 permutation).
// ---------------------------------------------------------------------------
__global__ __launch_bounds__(512, 2) void k_attn(const int* __restrict__ adj,
                                                 const float* __restrict__ fsrc,
                                                 const float* __restrict__ fdst,
                                                 const uint4* __restrict__ whfrag,
                                                 float* __restrict__ pacc,
                                                 float* __restrict__ pden) {
    __shared__ uint4 whL[NCH * 4 * 64];   // 128 KB: B-fragments for this j-split
    __shared__ float fsL[JSEG];           // 4 KB

    int t = threadIdx.x, wv = t >> 6, lane = t & 63;
    int bid = blockIdx.x;
    int rt = bid >> 3, q = bid & (NSPLIT - 1);
    int rowbase = rt * ROWS_B;

    // stage B-fragment slice + fsrc slice
    {
        const uint4* src = whfrag + (size_t)q * (NCH * 4 * 64);
#pragma unroll
        for (int it = 0; it < 16; ++it) whL[it * 512 + t] = src[it * 512 + t];
        if (t < 256) *(float4*)&fsL[t * 4] = *(const float4*)&fsrc[q * JSEG + t * 4];
    }
    __syncthreads();

    int r = lane & 15, g = lane >> 4;
    int row = rowbase + wv * 16 + r;
    float d = fdst[row];
    const int* arow = adj + (size_t)row * GN + q * JSEG + g * 4;

    f32x4 acc0 = {0.f, 0.f, 0.f, 0.f}, acc1 = acc0, acc2 = acc0, acc3 = acc0;
    float den = 0.f;

    iv4 pfa[PF], pfb[PF];
#pragma unroll
    for (int dd = 0; dd < PF; ++dd) {
        pfa[dd] = *(const iv4*)(arow + dd * 32);        // bytes [g*16, g*16+16) of chunk
        pfb[dd] = *(const iv4*)(arow + dd * 32 + 16);   // bytes [64+g*16, ...)
    }

    for (int cb = 0; cb < NCH; cb += PF) {
#pragma unroll
        for (int dd = 0; dd < PF; ++dd) {
            int ch = cb + dd;
            int ae[8] = {pfa[dd][0], pfa[dd][1], pfa[dd][2], pfa[dd][3],
                         pfb[dd][0], pfb[dd][1], pfb[dd][2], pfb[dd][3]};
            float4 s0 = *(const float4*)&fsL[ch * 32 + g * 4];
            float4 s1 = *(const float4*)&fsL[ch * 32 + 16 + g * 4];
            float se[8] = {s0.x, s0.y, s0.z, s0.w, s1.x, s1.y, s1.z, s1.w};

            // issue next adj chunk (wave-uniform guard; counted vmcnt keeps it async)
            int nch = ch + PF;
            if (nch < NCH) {
                pfa[dd] = *(const iv4*)(arow + nch * 32);
                pfb[dd] = *(const iv4*)(arow + nch * 32 + 16);
            }

            bf16x8 af;
            float ws = 0.f;
#pragma unroll
            for (int e = 0; e < 8; ++e) {
                float ev = d + se[e];                       // already log2e-scaled
                float lr = fmaxf(ev, 0.2f * ev);            // leakyrelu (scale-equivariant)
                float ex = __builtin_amdgcn_exp2f(lr);      // == exp(lrelu(d+s))
                float wvv = (ae[e] > 0) ? ex : 0.f;
                ws += wvv;
                af[e] = (__bf16)wvv;
            }
            den += ws;

            const uint4* bl = &whL[(ch * 4) * 64 + lane];
            uint4 b0 = bl[0], b1 = bl[64], b2 = bl[128], b3 = bl[192];
            acc0 = __builtin_amdgcn_mfma_f32_16x16x32_bf16(af, __builtin_bit_cast(bf16x8, b0), acc0, 0, 0, 0);
            acc1 = __builtin_amdgcn_mfma_f32_16x16x32_bf16(af, __builtin_bit_cast(bf16x8, b1), acc1, 0, 0, 0);
            acc2 = __builtin_amdgcn_mfma_f32_16x16x32_bf16(af, __builtin_bit_cast(bf16x8, b2), acc2, 0, 0, 0);
            acc3 = __builtin_amdgcn_mfma_f32_16x16x32_bf16(af, __builtin_bit_cast(bf16x8, b3), acc3, 0, 0, 0);
        }
    }

    // row denominator across the 4 k-groups
    den += __shfl_xor(den, 16);
    den += __shfl_xor(den, 32);

    // store partials. D layout: col = lane&15 (= r), row = g*4 + reg
    float* po = pacc + (size_t)q * (GN * FOUT);
    int orow = rowbase + wv * 16 + g * 4;
#pragma unroll
    for (int reg = 0; reg < 4; ++reg) {
        po[(size_t)(orow + reg) * FOUT +  0 + r] = acc0[reg];
        po[(size_t)(orow + reg) * FOUT + 16 + r] = acc1[reg];
        po[(size_t)(orow + reg) * FOUT + 32 + r] = acc2[reg];
        po[(size_t)(orow + reg) * FOUT + 48 + r] = acc3[reg];
    }
    if (g == 0) pden[(size_t)q * GN + row] = den;
}

// ---------------------------------------------------------------------------
// K3: combine partials, divide by denominator, ELU.
// ---------------------------------------------------------------------------
__global__ __launch_bounds__(256) void k_out(const float* __restrict__ pacc,
                                             const float* __restrict__ pden,
                                             float* __restrict__ out) {
    int idx = blockIdx.x * 256 + threadIdx.x;
    int i = idx >> 6;
    float num = 0.f, den = 0.f;
#pragma unroll
    for (int qq = 0; qq < NSPLIT; ++qq) {
        num += pacc[(size_t)qq * (GN * FOUT) + idx];
        den += pden[(size_t)qq * GN + i];
    }
    float v = (den != 0.f) ? num / den : 0.f;
    out[idx] = v > 0.f ? v : __expf(v) - 1.f;
}

// ---------------------------------------------------------------------------
extern "C" void kernel_launch(void* const* d_in, const int* in_sizes, int n_in,
                              void* d_out, int out_size, void* d_ws, size_t ws_size,
                              hipStream_t stream) {
    (void)in_sizes; (void)n_in; (void)out_size; (void)ws_size;
    const float* h   = (const float*)d_in[0];
    const int*   adj = (const int*)d_in[1];
    const float* W   = (const float*)d_in[2];
    const float* a   = (const float*)d_in[3];
    float* out = (float*)d_out;

    float* ws     = (float*)d_ws;
    float* fsrc   = ws;                                  // 8192 f
    float* fdst   = fsrc + GN;                           // 8192 f
    uint4* whfrag = (uint4*)(fdst + GN);                 // 65536 uint4 = 1 MB
    float* pacc   = (float*)(whfrag + (size_t)GN / 32 * 4 * 64); // NSPLIT*524288 f
    float* pden   = pacc + (size_t)NSPLIT * GN * FOUT;   // NSPLIT*8192 f

    k_wh  <<<GN / 32,                    256, 0, stream>>>(h, W, a, fsrc, fdst, whfrag);
    k_attn<<<(GN / ROWS_B) * NSPLIT,     512, 0, stream>>>(adj, fsrc, fdst, whfrag, pacc, pden);
    k_out <<<GN * FOUT / 256,            256, 0, stream>>>(pacc, pden, out);
}